// Round 8
// baseline (148.127 us; speedup 1.0000x reference)
//
#include <hip/hip_runtime.h>
#include <hip/hip_bf16.h>
#include <stdint.h>

typedef __attribute__((ext_vector_type(8))) short short8;
typedef __attribute__((ext_vector_type(4))) float float4v;

#define NHEADS 4
#define NNODES 4096
#define LOG2E 1.4426950408889634f
#define NJS 8                                  // j-split factor
#define PSTR ((size_t)NHEADS * NNODES * 64)    // partial-accum slice stride (floats)
#define LSTR ((size_t)NHEADS * NNODES)         // partial-l slice stride (floats)

__device__ __forceinline__ unsigned short f2b(float x) {
    union { float f; uint32_t u; } v; v.f = x;
    uint32_t u = v.u;
    uint32_t r = (u + 0x7FFFu + ((u >> 16) & 1u)) >> 16;
    return (unsigned short)r;
}
__device__ __forceinline__ float b2f(unsigned short s) {
    union { uint32_t u; float f; } v; v.u = ((uint32_t)s) << 16;
    return v.f;
}
__device__ __forceinline__ uint32_t cvtpk(float lo, float hi) {
    uint32_t r;
    asm("v_cvt_pk_bf16_f32 %0, %1, %2" : "=v"(r) : "v"(lo), "v"(hi));
    return r;
}

#define AS1 __attribute__((address_space(1)))
#define AS3 __attribute__((address_space(3)))
__device__ __forceinline__ void gl_lds16(const void* g, void* l) {
    __builtin_amdgcn_global_load_lds((const AS1 unsigned int*)g,
                                     (AS3 unsigned int*)l, 16, 0, 0);
}

// ---- fused preprocessing: ballot-free adjacency pack + x cast + W transposes ----
__global__ __launch_bounds__(256) void k_pre(const int* __restrict__ adj,
                                             unsigned short* __restrict__ mask16,
                                             const float* __restrict__ x,
                                             unsigned short* __restrict__ xbf,
                                             const float* __restrict__ W1,
                                             unsigned short* __restrict__ WT1,
                                             const float* __restrict__ W2,
                                             unsigned short* __restrict__ WT2,
                                             const float* __restrict__ W3,
                                             unsigned short* __restrict__ WT3) {
    int b = blockIdx.x;
    if (b < 4096) {                         // pack: 16 consecutive j per thread, no ballot
        const int4* ap = (const int4*)(adj + ((size_t)b << 12)) + threadIdx.x * 4;
        int4 a0 = ap[0], a1 = ap[1], a2 = ap[2], a3 = ap[3];
        int v[16] = {a0.x, a0.y, a0.z, a0.w, a1.x, a1.y, a1.z, a1.w,
                     a2.x, a2.y, a2.z, a2.w, a3.x, a3.y, a3.z, a3.w};
        uint32_t bits = 0;
#pragma unroll
        for (int k = 0; k < 16; ++k) bits |= (uint32_t)(v[k] != 0) << k;
        mask16[(b << 8) + threadIdx.x] = (unsigned short)bits;
        return;
    }
    int i = (b - 4096) * 256 + threadIdx.x;
    if (i < 524288) {                       // x: 4096*512 f32, 4 per thread
        float4v v = ((const float4v*)x)[i];
        uint2 r;
        r.x = cvtpk(v[0], v[1]);
        r.y = cvtpk(v[2], v[3]);
        ((uint2*)xbf)[i] = r;
    } else if (i < 524288 + 131072) {       // W1 [4][512][64] -> WT1 [4][64][512]
        int j = i - 524288;
        int o = j & 63, f = (j >> 6) & 511, h = j >> 15;
        WT1[((size_t)(h * 64 + o)) * 512 + f] = f2b(W1[j]);
    } else if (i < 524288 + 131072 + 32768) { // W2 [4][256][32] -> WT2 [4][32][256]
        int j = i - 655360;
        int o = j & 31, f = (j >> 5) & 255, h = j >> 13;
        WT2[((size_t)(h * 32 + o)) * 256 + f] = f2b(W2[j]);
    } else if (i < 524288 + 131072 + 32768 + 8192) { // W3 [4][128][16] -> WT3 [4][16][128]
        int j = i - 688128;
        int o = j & 15, f = (j >> 4) & 127, h = j >> 11;
        WT3[((size_t)(h * 16 + o)) * 128 + f] = f2b(W3[j]);
    }
}

// ---- Wh = x @ W (4-wave K-split) + fused f1/f2 epilogue; writes WhT bf16 only ----
template <int Fin, int O>
__global__ __launch_bounds__(256) void k_whgemm(const unsigned short* __restrict__ A,
                                                const unsigned short* __restrict__ WT,
                                                const float* __restrict__ avec,
                                                unsigned short* __restrict__ WhT,
                                                float* __restrict__ f1,
                                                float* __restrict__ f2) {
    __shared__ float scc[4][16][64];
    constexpr int HPB = 64 / O;           // complete heads per col-group
    const int rt = blockIdx.x & 255, cg = blockIdx.x >> 8;
    const int wv = threadIdx.x >> 6, lane = threadIdx.x & 63;
    const int il = lane & 15, g = lane >> 4;
    constexpr int kpw = Fin >> 2;
    const int k0 = wv * kpw;
    float4v acc[4];
#pragma unroll
    for (int ot = 0; ot < 4; ++ot) acc[ot] = (float4v){0.f, 0.f, 0.f, 0.f};
    const unsigned short* Arow = A + (size_t)(rt * 16 + il) * Fin + k0 + 8 * g;
    const unsigned short* Bcol = WT + (size_t)(cg * 64 + il) * Fin + k0 + 8 * g;
#pragma unroll
    for (int k = 0; k < kpw; k += 32) {
        short8 af = *(const short8*)(Arow + k);
#pragma unroll
        for (int ot = 0; ot < 4; ++ot) {
            short8 bf = *(const short8*)(Bcol + (size_t)ot * 16 * Fin + k);
            acc[ot] = __builtin_amdgcn_mfma_f32_16x16x32_bf16(af, bf, acc[ot], 0, 0, 0);
        }
    }
#pragma unroll
    for (int ot = 0; ot < 4; ++ot)
#pragma unroll
        for (int r = 0; r < 4; ++r) scc[wv][g * 4 + r][ot * 16 + il] = acc[ot][r];
    __syncthreads();
    // epilogue 1: WhT bf16 [H][O][N]
    for (int e = threadIdx.x; e < 1024; e += 256) {
        int row = e >> 6, col = e & 63;
        float v = scc[0][row][col] + scc[1][row][col] + scc[2][row][col] + scc[3][row][col];
        int gc = cg * 64 + col;
        int hh = gc / O, o = gc % O;
        WhT[((size_t)(hh * O + o)) * NNODES + rt * 16 + row] = f2b(v);
    }
    // epilogue 2: f1/f2 (each block covers complete heads -> no atomics)
    {
        int hl = lane / O, o = lane % O;
        int h = cg * HPB + hl;
        float av1 = avec[h * 2 * O + o];
        float av2 = avec[h * 2 * O + O + o];
#pragma unroll
        for (int r = 0; r < 4; ++r) {
            int row = wv * 4 + r;
            float v = scc[0][row][lane] + scc[1][row][lane] + scc[2][row][lane] + scc[3][row][lane];
            float s1 = v * av1, s2 = v * av2;
#pragma unroll
            for (int d = O / 2; d > 0; d >>= 1) {
                s1 += __shfl_xor(s1, d);
                s2 += __shfl_xor(s2, d);
            }
            if (o == 0) {
                int n = rt * 16 + row;
                f1[h * NNODES + n] = s1 * LOG2E;
                f2[h * NNODES + n] = s2 * LOG2E;
            }
        }
    }
}

// ---- fused attention PV: 3-buffer counted-vmcnt pipeline (DMA-only window), js=8 ----
template <int O>
__global__ __launch_bounds__(256, 5)
void k_pv(const uint32_t* __restrict__ mask,
          const float* __restrict__ f1L,
          const float* __restrict__ f2L,
          const unsigned short* __restrict__ WhT,
          float* __restrict__ pacc,
          float* __restrict__ lpart) {
    constexpr int TJ  = (O == 16) ? 128 : 64;   // j per tile
    constexpr int NTT = 512 / TJ;               // tiles per block
    constexpr int NT  = O / 16;                 // output 16-col tiles
    constexpr int CH  = O * TJ / 8;             // 16B chunks per tile
    constexpr int SPT = CH / 256;               // stage ops per thread per tile
    constexpr int CPR = TJ / 8;                 // chunks per row
    constexpr int NSUB = TJ / 32;               // 32-j subtiles per tile
    __shared__ unsigned short bt[3][CH * 8];
    __shared__ float sf2[512];
    const int b = blockIdx.x;
    const int js = b & 7, rt = (b >> 3) & 63, h = b >> 9;
    const int tid = threadIdx.x, wv = tid >> 6, lane = tid & 63;
    const int il = lane & 15, g = lane >> 4;
    const int j0b = js * 512;
    const float* f2h = f2L + h * NNODES;
    const unsigned short* WB0 = WhT + (size_t)h * O * NNODES;
    const int nrow = wv * 16 + il;

    // ---- prologue A: ALL plain VMEM loads (f1i + full slice mask -> regs), then drain
    const float f1i = f1L[h * NNODES + rt * 64 + nrow];
    const uint32_t* mrow = mask + (size_t)(rt * 64 + nrow) * 128 + js * 16;
    uint32_t mw[16];
    {
        uint4 a = *(const uint4*)(mrow);
        uint4 c = *(const uint4*)(mrow + 4);
        uint4 d = *(const uint4*)(mrow + 8);
        uint4 e = *(const uint4*)(mrow + 12);
        mw[0] = a.x;  mw[1] = a.y;  mw[2] = a.z;  mw[3] = a.w;
        mw[4] = c.x;  mw[5] = c.y;  mw[6] = c.z;  mw[7] = c.w;
        mw[8] = d.x;  mw[9] = d.y;  mw[10] = d.z; mw[11] = d.w;
        mw[12] = e.x; mw[13] = e.y; mw[14] = e.z; mw[15] = e.w;
    }
    asm volatile("s_waitcnt vmcnt(0)" ::: "memory");
    __builtin_amdgcn_sched_barrier(0);

    // ---- prologue B: DMA-only window (global_load_lds are mutually ordered)
    auto stage_tile = [&](int t, int buf) {
#pragma unroll
        for (int q = 0; q < SPT; ++q) {
            int s = q * 256 + tid;
            int o = s / CPR, c = s % CPR;
            int cs = c ^ (o & (CPR - 1));
            gl_lds16(WB0 + (size_t)o * NNODES + j0b + t * TJ + 8 * cs,
                     (char*)&bt[buf][0] + s * 16);
        }
    };
    if (tid < 128) gl_lds16(f2h + j0b + tid * 4, (char*)sf2 + tid * 16);  // issued first
    stage_tile(0, 0);
    stage_tile(1, 1);
    // waves 0-1: outstanding 2*SPT+1, wait leaves SPT -> completed f2+tile0
    // waves 2-3: outstanding 2*SPT,   wait leaves SPT -> completed tile0
    asm volatile("s_waitcnt vmcnt(%0)" :: "i"(SPT) : "memory");
    __builtin_amdgcn_sched_barrier(0);
    __builtin_amdgcn_s_barrier();

    float4v acc[NT];
#pragma unroll
    for (int ot = 0; ot < NT; ++ot) acc[ot] = (float4v){0.f, 0.f, 0.f, 0.f};
    float4v accl = (float4v){0.f, 0.f, 0.f, 0.f};
    short8 bones;
#pragma unroll
    for (int q = 0; q < 8; ++q) bones[q] = (il == 0) ? (short)0x3F80 : (short)0;

    auto compute = [&](int t) {     // t is compile-time (unrolled callers)
        const char* btc = (const char*)&bt[t % 3][0];
        const float* fp0 = sf2 + t * TJ + 8 * g;
#pragma unroll
        for (int s = 0; s < NSUB; ++s) {
            short8 B[NT];
#pragma unroll
            for (int ot = 0; ot < NT; ++ot) {
                int o = ot * 16 + il;
                B[ot] = *(const short8*)(btc + o * (CPR * 16) +
                                         16 * (((s << 2) + g) ^ (o & (CPR - 1))));
            }
            const float* fp = fp0 + s * 32;
            float4v fa = *(const float4v*)fp;
            float4v fb = *(const float4v*)(fp + 4);
            uint32_t word = mw[t * NSUB + s];
            uint32_t bits = (word >> (8 * g)) & 0xFFu;
            float p[8];
#pragma unroll
            for (int bb = 0; bb < 8; ++bb) {
                float sv = f1i + ((bb < 4) ? fa[bb] : fb[bb - 4]);
                sv = fmaxf(sv, 0.2f * sv);
                float pv = __builtin_amdgcn_exp2f(sv);
                p[bb] = ((bits >> bb) & 1u) ? pv : 0.f;
            }
            union { short8 s8; uint32_t u[4]; } pu;
            pu.u[0] = cvtpk(p[0], p[1]);
            pu.u[1] = cvtpk(p[2], p[3]);
            pu.u[2] = cvtpk(p[4], p[5]);
            pu.u[3] = cvtpk(p[6], p[7]);
#pragma unroll
            for (int ot = 0; ot < NT; ++ot)
                acc[ot] = __builtin_amdgcn_mfma_f32_16x16x32_bf16(pu.s8, B[ot], acc[ot], 0, 0, 0);
            accl = __builtin_amdgcn_mfma_f32_16x16x32_bf16(pu.s8, bones, accl, 0, 0, 0);
        }
    };

#pragma unroll
    for (int t = 0; t < NTT - 2; ++t) {
        stage_tile(t + 2, (t + 2) % 3);
        compute(t);
        asm volatile("s_waitcnt vmcnt(%0)" :: "i"(SPT) : "memory");
        __builtin_amdgcn_sched_barrier(0);
        __builtin_amdgcn_s_barrier();
    }
    compute(NTT - 2);
    asm volatile("s_waitcnt vmcnt(0)" ::: "memory");
    __builtin_amdgcn_sched_barrier(0);
    __builtin_amdgcn_s_barrier();
    compute(NTT - 1);

    // non-atomic disjoint partial stores (slice js owns its buffer)
    float* pj = pacc + js * PSTR + (size_t)h * NNODES * O;
#pragma unroll
    for (int ot = 0; ot < NT; ++ot)
#pragma unroll
        for (int r = 0; r < 4; ++r)
            pj[(size_t)(rt * 64 + wv * 16 + g * 4 + r) * O + ot * 16 + il] = acc[ot][r];
    if (il == 0) {
        float* lj = lpart + js * LSTR + h * NNODES;
#pragma unroll
        for (int r = 0; r < 4; ++r)
            lj[rt * 64 + wv * 16 + g * 4 + r] = accl[r];
    }
}

// ---- finalize (stages 1,2): sum 8 partials, divide, elu, head-concat to bf16 ----
template <int O>
__global__ __launch_bounds__(256) void k_fin(const float* __restrict__ pacc,
                                             const float* __restrict__ lpart,
                                             unsigned short* __restrict__ hout) {
    constexpr int HO = NHEADS * O;
    int e = blockIdx.x * 256 + threadIdx.x;
    int o = e % O;
    int n = (e / O) & (NNODES - 1);
    int h = e / (O * NNODES);
    size_t idx = ((size_t)h * NNODES + n) * O + o;
    int li = h * NNODES + n;
    float s = 0.f, l = 0.f;
#pragma unroll
    for (int k = 0; k < NJS; ++k) {
        s += pacc[k * PSTR + idx];
        l += lpart[k * LSTR + li];
    }
    float v = s / l;
    v = (v > 0.f) ? v : (__expf(v) - 1.f);
    hout[(size_t)n * HO + h * O + o] = f2b(v);
}

// ---- stage-3 finalize fused with final linear + log_softmax (LDS handoff) ----
__global__ __launch_bounds__(256) void k_fin3final(const float* __restrict__ pacc,
                                                   const float* __restrict__ lpart,
                                                   const float* __restrict__ Wlin,
                                                   const float* __restrict__ blin,
                                                   float* __restrict__ out) {
    __shared__ float sh3[4][64];
    const int tid = threadIdx.x;
    const int n0 = blockIdx.x * 4;
    {   // finalize 4 rows x 64 features (h*16+o), one element per thread
        int r = tid >> 6, hh = (tid >> 4) & 3, o = tid & 15;
        int n = n0 + r;
        size_t idx = ((size_t)hh * NNODES + n) * 16 + o;
        int li = hh * NNODES + n;
        float s = 0.f, l = 0.f;
#pragma unroll
        for (int k = 0; k < NJS; ++k) {
            s += pacc[k * PSTR + idx];
            l += lpart[k * LSTR + li];
        }
        float v = s / l;
        v = (v > 0.f) ? v : (__expf(v) - 1.f);
        sh3[r][hh * 16 + o] = v;
    }
    __syncthreads();
    int rr = tid >> 6, lane = tid & 63;
    int n = n0 + rr;
    float logit = 0.f;
    if (lane < 40) {
        logit = blin[lane];
#pragma unroll
        for (int k = 0; k < 64; ++k) logit += sh3[rr][k] * Wlin[k * 40 + lane];
    }
    float mv = (lane < 40) ? logit : -3.0e38f;
    for (int d = 32; d > 0; d >>= 1) mv = fmaxf(mv, __shfl_xor(mv, d));
    float ex = (lane < 40) ? __expf(logit - mv) : 0.f;
    for (int d = 32; d > 0; d >>= 1) ex += __shfl_xor(ex, d);
    if (lane < 40) out[n * 40 + lane] = logit - mv - logf(ex);
}

template <int Fin, int O>
static void run_stage(hipStream_t stream, const uint32_t* mask, const unsigned short* xin,
                      const unsigned short* WT, const float* avec,
                      unsigned short* WhT, float* f1, float* f2,
                      float* pacc, float* lpart) {
    constexpr int CG = (NHEADS * O) / 64;
    k_whgemm<Fin, O><<<256 * CG, 256, 0, stream>>>(xin, WT, avec, WhT, f1, f2);
    k_pv<O><<<4 * 64 * NJS, 256, 0, stream>>>(mask, f1, f2, WhT, pacc, lpart);
}

extern "C" void kernel_launch(void* const* d_in, const int* in_sizes, int n_in,
                              void* d_out, int out_size, void* d_ws, size_t ws_size,
                              hipStream_t stream) {
    const float* x    = (const float*)d_in[0];
    const int*   adj  = (const int*)d_in[1];
    const float* W1   = (const float*)d_in[2];
    const float* a1   = (const float*)d_in[3];
    const float* W2   = (const float*)d_in[4];
    const float* a2   = (const float*)d_in[5];
    const float* W3   = (const float*)d_in[6];
    const float* a3   = (const float*)d_in[7];
    const float* Wlin = (const float*)d_in[8];
    const float* blin = (const float*)d_in[9];
    float* out = (float*)d_out;

    char* ws = (char*)d_ws;
    uint32_t*       mask = (uint32_t*)ws;                                   // 2 MB
    unsigned short* xbf  = (unsigned short*)(ws + (2u << 20));              // 4 MB
    unsigned short* WhT  = (unsigned short*)(ws + (6u << 20));              // 2 MB
    unsigned short* WT1  = (unsigned short*)(ws + (8u << 20));              // 256 KB
    unsigned short* WT2  = (unsigned short*)(ws + (8u << 20) + (256u << 10)); // 64 KB
    unsigned short* WT3  = (unsigned short*)(ws + (8u << 20) + (320u << 10)); // 16 KB
    float*          f1   = (float*)(ws + (8u << 20) + (384u << 10));        // 64 KB
    float*          f2   = (float*)(ws + (8u << 20) + (448u << 10));        // 64 KB
    float*          lpart= (float*)(ws + (8u << 20) + (512u << 10));        // 512 KB
    float*          pacc = (float*)(ws + (9u << 20));                       // 32 MB

    k_pre<<<4096 + 2720, 256, 0, stream>>>(adj, (unsigned short*)mask, x, xbf,
                                           W1, WT1, W2, WT2, W3, WT3);

    run_stage<512, 64>(stream, mask, xbf, WT1, a1, WhT, f1, f2, pacc, lpart);
    k_fin<64><<<NHEADS * NNODES * 64 / 256, 256, 0, stream>>>(pacc, lpart, xbf);
    run_stage<256, 32>(stream, mask, xbf, WT2, a2, WhT, f1, f2, pacc, lpart);
    k_fin<32><<<NHEADS * NNODES * 32 / 256, 256, 0, stream>>>(pacc, lpart, xbf);
    run_stage<128, 16>(stream, mask, xbf, WT3, a3, WhT, f1, f2, pacc, lpart);
    k_fin3final<<<NNODES / 4, 256, 0, stream>>>(pacc, lpart, Wlin, blin, out);
}

// Round 10
// 142.259 us; speedup vs baseline: 1.0413x; 1.0413x over previous
//
#include <hip/hip_runtime.h>
#include <hip/hip_bf16.h>
#include <stdint.h>

typedef __attribute__((ext_vector_type(8))) short short8;
typedef __attribute__((ext_vector_type(4))) float float4v;

#define NHEADS 4
#define NNODES 4096
#define LOG2E 1.4426950408889634f
#define NJS 4
#define PSTR ((size_t)NHEADS * NNODES * 64)    // partial-accum slice stride (floats)
#define LSTR ((size_t)NHEADS * NNODES)         // partial-l slice stride (floats)

__device__ __forceinline__ unsigned short f2b(float x) {
    union { float f; uint32_t u; } v; v.f = x;
    uint32_t u = v.u;
    uint32_t r = (u + 0x7FFFu + ((u >> 16) & 1u)) >> 16;
    return (unsigned short)r;
}
__device__ __forceinline__ uint32_t cvtpk(float lo, float hi) {
    uint32_t r;
    asm("v_cvt_pk_bf16_f32 %0, %1, %2" : "=v"(r) : "v"(lo), "v"(hi));
    return r;
}

#define AS1 __attribute__((address_space(1)))
#define AS3 __attribute__((address_space(3)))
__device__ __forceinline__ void gl_lds16(const void* g, void* l) {
    __builtin_amdgcn_global_load_lds((const AS1 unsigned int*)g,
                                     (AS3 unsigned int*)l, 16, 0, 0);
}

// ---- fused preprocessing: ballot-free adjacency pack + x cast + W transposes ----
__global__ __launch_bounds__(256) void k_pre(const int* __restrict__ adj,
                                             unsigned short* __restrict__ mask16,
                                             const float* __restrict__ x,
                                             unsigned short* __restrict__ xbf,
                                             const float* __restrict__ W1,
                                             unsigned short* __restrict__ WT1,
                                             const float* __restrict__ W2,
                                             unsigned short* __restrict__ WT2,
                                             const float* __restrict__ W3,
                                             unsigned short* __restrict__ WT3) {
    int b = blockIdx.x;
    if (b < 4096) {                         // pack: 16 consecutive j per thread, no ballot
        const int4* ap = (const int4*)(adj + ((size_t)b << 12)) + threadIdx.x * 4;
        int4 a0 = ap[0], a1 = ap[1], a2 = ap[2], a3 = ap[3];
        int v[16] = {a0.x, a0.y, a0.z, a0.w, a1.x, a1.y, a1.z, a1.w,
                     a2.x, a2.y, a2.z, a2.w, a3.x, a3.y, a3.z, a3.w};
        uint32_t bits = 0;
#pragma unroll
        for (int k = 0; k < 16; ++k) bits |= (uint32_t)(v[k] != 0) << k;
        mask16[(b << 8) + threadIdx.x] = (unsigned short)bits;
        return;
    }
    int i = (b - 4096) * 256 + threadIdx.x;
    if (i < 524288) {                       // x: 4096*512 f32, 4 per thread
        float4v v = ((const float4v*)x)[i];
        uint2 r;
        r.x = cvtpk(v[0], v[1]);
        r.y = cvtpk(v[2], v[3]);
        ((uint2*)xbf)[i] = r;
    } else if (i < 524288 + 131072) {       // W1 [4][512][64] -> WT1 [4][64][512]
        int j = i - 524288;
        int o = j & 63, f = (j >> 6) & 511, h = j >> 15;
        WT1[((size_t)(h * 64 + o)) * 512 + f] = f2b(W1[j]);
    } else if (i < 524288 + 131072 + 32768) { // W2 [4][256][32] -> WT2 [4][32][256]
        int j = i - 655360;
        int o = j & 31, f = (j >> 5) & 255, h = j >> 13;
        WT2[((size_t)(h * 32 + o)) * 256 + f] = f2b(W2[j]);
    } else if (i < 524288 + 131072 + 32768 + 8192) { // W3 [4][128][16] -> WT3 [4][16][128]
        int j = i - 688128;
        int o = j & 15, f = (j >> 4) & 127, h = j >> 11;
        WT3[((size_t)(h * 16 + o)) * 128 + f] = f2b(W3[j]);
    }
}

// ---- Wh = x @ W (4-wave K-split) + fused f1/f2 epilogue; writes WhT bf16 only ----
template <int Fin, int O>
__global__ __launch_bounds__(256) void k_whgemm(const unsigned short* __restrict__ A,
                                                const unsigned short* __restrict__ WT,
                                                const float* __restrict__ avec,
                                                unsigned short* __restrict__ WhT,
                                                float* __restrict__ f1,
                                                float* __restrict__ f2) {
    __shared__ float scc[4][16][64];
    constexpr int HPB = 64 / O;           // complete heads per col-group
    const int rt = blockIdx.x & 255, cg = blockIdx.x >> 8;
    const int wv = threadIdx.x >> 6, lane = threadIdx.x & 63;
    const int il = lane & 15, g = lane >> 4;
    constexpr int kpw = Fin >> 2;
    const int k0 = wv * kpw;
    float4v acc[4];
#pragma unroll
    for (int ot = 0; ot < 4; ++ot) acc[ot] = (float4v){0.f, 0.f, 0.f, 0.f};
    const unsigned short* Arow = A + (size_t)(rt * 16 + il) * Fin + k0 + 8 * g;
    const unsigned short* Bcol = WT + (size_t)(cg * 64 + il) * Fin + k0 + 8 * g;
#pragma unroll
    for (int k = 0; k < kpw; k += 32) {
        short8 af = *(const short8*)(Arow + k);
#pragma unroll
        for (int ot = 0; ot < 4; ++ot) {
            short8 bf = *(const short8*)(Bcol + (size_t)ot * 16 * Fin + k);
            acc[ot] = __builtin_amdgcn_mfma_f32_16x16x32_bf16(af, bf, acc[ot], 0, 0, 0);
        }
    }
#pragma unroll
    for (int ot = 0; ot < 4; ++ot)
#pragma unroll
        for (int r = 0; r < 4; ++r) scc[wv][g * 4 + r][ot * 16 + il] = acc[ot][r];
    __syncthreads();
    // epilogue 1: WhT bf16 [H][O][N]
    for (int e = threadIdx.x; e < 1024; e += 256) {
        int row = e >> 6, col = e & 63;
        float v = scc[0][row][col] + scc[1][row][col] + scc[2][row][col] + scc[3][row][col];
        int gc = cg * 64 + col;
        int hh = gc / O, o = gc % O;
        WhT[((size_t)(hh * O + o)) * NNODES + rt * 16 + row] = f2b(v);
    }
    // epilogue 2: f1/f2 (each block covers complete heads -> no atomics)
    {
        int hl = lane / O, o = lane % O;
        int h = cg * HPB + hl;
        float av1 = avec[h * 2 * O + o];
        float av2 = avec[h * 2 * O + O + o];
#pragma unroll
        for (int r = 0; r < 4; ++r) {
            int row = wv * 4 + r;
            float v = scc[0][row][lane] + scc[1][row][lane] + scc[2][row][lane] + scc[3][row][lane];
            float s1 = v * av1, s2 = v * av2;
#pragma unroll
            for (int d = O / 2; d > 0; d >>= 1) {
                s1 += __shfl_xor(s1, d);
                s2 += __shfl_xor(s2, d);
            }
            if (o == 0) {
                int n = rt * 16 + row;
                f1[h * NNODES + n] = s1 * LOG2E;
                f2[h * NNODES + n] = s2 * LOG2E;
            }
        }
    }
}

// ---- stage one 64-j B tile ([O rows][64 j] bf16) into LDS, source-swizzled ----
template <int O>
__device__ __forceinline__ void stage_tile_f(const unsigned short* WB0, int j0,
                                             char* dst, int tid) {
    constexpr int CH = O * 8;   // 16B chunks
#pragma unroll
    for (int q = 0; q < CH; q += 256) {
        int s = q + tid;
        if (CH >= 256 || s < CH) {
            int o = s >> 3, c = s & 7;
            int cg = c ^ (o & 7);
            gl_lds16(WB0 + (size_t)o * NNODES + j0 + 8 * cg, dst + s * 16);
        }
    }
}

// ---- fused attention PV: 4-buffer 3-in-flight counted-vmcnt pipeline, js=4 ----
template <int O>
__global__ __launch_bounds__(256, 4) void k_pv(const uint32_t* __restrict__ mask,
                                               const float* __restrict__ f1L,
                                               const float* __restrict__ f2L,
                                               const unsigned short* __restrict__ WhT,
                                               float* __restrict__ pacc,
                                               float* __restrict__ lpart) {
    constexpr int NT = O / 16;
    constexpr int CH = O * 8;
    constexpr int SPT = (O == 64) ? 2 : 1;   // stage ops per participating thread per tile
    constexpr int NTT = 16;
    __shared__ unsigned short bt[4][CH * 8];
    __shared__ float sf2[1024];
    __shared__ uint32_t smask[64][34];       // pad 34 -> conflict-free b64 reads
    const int b = blockIdx.x;
    const int js = b & 3, rt = (b >> 2) & 63, h = b >> 8;
    const int tid = threadIdx.x, wv = tid >> 6, lane = tid & 63;
    const int il = lane & 15, g = lane >> 4;
    const int j0b = js * 1024;
    const float* f2h = f2L + h * NNODES;
    const unsigned short* WB0 = WhT + (size_t)h * O * NNODES;
    const int nrow = wv * 16 + il;
    const float f1i = f1L[h * NNODES + rt * 64 + nrow];

    // ---- prologue A: masks -> regs, drain, masks -> LDS (no plain VMEM after this)
    {
        int r = tid >> 2, c = (tid & 3) * 8;
        const uint32_t* mg = mask + (size_t)(rt * 64 + r) * 128 + js * 32 + c;
        uint4 m0 = *(const uint4*)mg;
        uint4 m1 = *(const uint4*)(mg + 4);
        asm volatile("s_waitcnt vmcnt(0)" ::: "memory");
        uint32_t* dstm = &smask[r][c];
        *(uint2*)(dstm + 0) = make_uint2(m0.x, m0.y);
        *(uint2*)(dstm + 2) = make_uint2(m0.z, m0.w);
        *(uint2*)(dstm + 4) = make_uint2(m1.x, m1.y);
        *(uint2*)(dstm + 6) = make_uint2(m1.z, m1.w);
    }
    // ---- prologue B: DMA-only window; 3 tiles in flight
    gl_lds16(f2h + j0b + tid * 4, (char*)sf2 + tid * 16);      // issued first
    stage_tile_f<O>(WB0, j0b, (char*)&bt[0][0], tid);
    stage_tile_f<O>(WB0, j0b + 64, (char*)&bt[1][0], tid);
    stage_tile_f<O>(WB0, j0b + 128, (char*)&bt[2][0], tid);
    // participating threads: outstanding 3*SPT+1; leave 2*SPT -> f2 + tile0 landed
    asm volatile("s_waitcnt vmcnt(%0) lgkmcnt(0)" :: "i"(2 * SPT) : "memory");
    __builtin_amdgcn_sched_barrier(0);
    __builtin_amdgcn_s_barrier();

    float4v acc[NT];
#pragma unroll
    for (int ot = 0; ot < NT; ++ot) acc[ot] = (float4v){0.f, 0.f, 0.f, 0.f};
    float4v accl = (float4v){0.f, 0.f, 0.f, 0.f};
    short8 bones;
#pragma unroll
    for (int q = 0; q < 8; ++q) bones[q] = (il == 0) ? (short)0x3F80 : (short)0;

    auto compute = [&](int t) {      // t compile-time (unrolled callers)
        const char* btc = (const char*)&bt[t & 3][0];
        uint2 mw = *(const uint2*)&smask[nrow][2 * t];
        const float* fp0 = sf2 + t * 64 + 8 * g;
#pragma unroll
        for (int s = 0; s < 2; ++s) {
            short8 B[NT];
#pragma unroll
            for (int ot = 0; ot < NT; ++ot) {
                int o = ot * 16 + il;
                B[ot] = *(const short8*)(btc + o * 128 + 16 * (((s << 2) + g) ^ (o & 7)));
            }
            const float* fp = fp0 + s * 32;
            float4v fa = *(const float4v*)fp;
            float4v fb = *(const float4v*)(fp + 4);
            uint32_t word = s ? mw.y : mw.x;
            uint32_t bits = (word >> (8 * g)) & 0xFFu;
            float p[8];
#pragma unroll
            for (int bb = 0; bb < 8; ++bb) {
                float sv = f1i + ((bb < 4) ? fa[bb] : fb[bb - 4]);
                sv = fmaxf(sv, 0.2f * sv);
                float pv = __builtin_amdgcn_exp2f(sv);
                p[bb] = ((bits >> bb) & 1u) ? pv : 0.f;
            }
            union { short8 s8; uint32_t u[4]; } pu;
            pu.u[0] = cvtpk(p[0], p[1]);
            pu.u[1] = cvtpk(p[2], p[3]);
            pu.u[2] = cvtpk(p[4], p[5]);
            pu.u[3] = cvtpk(p[6], p[7]);
#pragma unroll
            for (int ot = 0; ot < NT; ++ot)
                acc[ot] = __builtin_amdgcn_mfma_f32_16x16x32_bf16(pu.s8, B[ot], acc[ot], 0, 0, 0);
            accl = __builtin_amdgcn_mfma_f32_16x16x32_bf16(pu.s8, bones, accl, 0, 0, 0);
        }
    };

#pragma unroll
    for (int t = 0; t < NTT - 3; ++t) {
        stage_tile_f<O>(WB0, j0b + (t + 3) * 64, (char*)&bt[(t + 3) & 3][0], tid);
        compute(t);
        asm volatile("s_waitcnt vmcnt(%0)" :: "i"(2 * SPT) : "memory");  // t+1 landed
        __builtin_amdgcn_sched_barrier(0);
        __builtin_amdgcn_s_barrier();
    }
    compute(NTT - 3);
    asm volatile("s_waitcnt vmcnt(%0)" :: "i"(SPT) : "memory");          // NTT-2 landed
    __builtin_amdgcn_sched_barrier(0);
    __builtin_amdgcn_s_barrier();
    compute(NTT - 2);
    asm volatile("s_waitcnt vmcnt(0)" ::: "memory");                     // NTT-1 landed
    __builtin_amdgcn_sched_barrier(0);
    __builtin_amdgcn_s_barrier();
    compute(NTT - 1);

    // non-atomic disjoint partial stores (slice js owns its buffer)
    float* pj = pacc + js * PSTR + (size_t)h * NNODES * O;
#pragma unroll
    for (int ot = 0; ot < NT; ++ot)
#pragma unroll
        for (int r = 0; r < 4; ++r)
            pj[(size_t)(rt * 64 + wv * 16 + g * 4 + r) * O + ot * 16 + il] = acc[ot][r];
    if (il == 0) {
        float* lj = lpart + js * LSTR + h * NNODES;
#pragma unroll
        for (int r = 0; r < 4; ++r)
            lj[rt * 64 + wv * 16 + g * 4 + r] = accl[r];
    }
}

// ---- finalize (stages 1,2): sum 4 partials, divide, elu, head-concat to bf16 ----
template <int O>
__global__ __launch_bounds__(256) void k_fin(const float* __restrict__ pacc,
                                             const float* __restrict__ lpart,
                                             unsigned short* __restrict__ hout) {
    constexpr int HO = NHEADS * O;
    int e = blockIdx.x * 256 + threadIdx.x;
    int o = e % O;
    int n = (e / O) & (NNODES - 1);
    int h = e / (O * NNODES);
    size_t idx = ((size_t)h * NNODES + n) * O + o;
    int li = h * NNODES + n;
    float s = 0.f, l = 0.f;
#pragma unroll
    for (int k = 0; k < NJS; ++k) {
        s += pacc[k * PSTR + idx];
        l += lpart[k * LSTR + li];
    }
    float v = s / l;
    v = (v > 0.f) ? v : (__expf(v) - 1.f);
    hout[(size_t)n * HO + h * O + o] = f2b(v);
}

// ---- stage-3 finalize fused with final linear + log_softmax (LDS handoff) ----
__global__ __launch_bounds__(256) void k_fin3final(const float* __restrict__ pacc,
                                                   const float* __restrict__ lpart,
                                                   const float* __restrict__ Wlin,
                                                   const float* __restrict__ blin,
                                                   float* __restrict__ out) {
    __shared__ float sh3[4][64];
    const int tid = threadIdx.x;
    const int n0 = blockIdx.x * 4;
    {   // finalize 4 rows x 64 features (h*16+o), one element per thread
        int r = tid >> 6, hh = (tid >> 4) & 3, o = tid & 15;
        int n = n0 + r;
        size_t idx = ((size_t)hh * NNODES + n) * 16 + o;
        int li = hh * NNODES + n;
        float s = 0.f, l = 0.f;
#pragma unroll
        for (int k = 0; k < NJS; ++k) {
            s += pacc[k * PSTR + idx];
            l += lpart[k * LSTR + li];
        }
        float v = s / l;
        v = (v > 0.f) ? v : (__expf(v) - 1.f);
        sh3[r][hh * 16 + o] = v;
    }
    __syncthreads();
    int rr = tid >> 6, lane = tid & 63;
    int n = n0 + rr;
    float logit = 0.f;
    if (lane < 40) {
        logit = blin[lane];
#pragma unroll
        for (int k = 0; k < 64; ++k) logit += sh3[rr][k] * Wlin[k * 40 + lane];
    }
    float mv = (lane < 40) ? logit : -3.0e38f;
    for (int d = 32; d > 0; d >>= 1) mv = fmaxf(mv, __shfl_xor(mv, d));
    float ex = (lane < 40) ? __expf(logit - mv) : 0.f;
    for (int d = 32; d > 0; d >>= 1) ex += __shfl_xor(ex, d);
    if (lane < 40) out[n * 40 + lane] = logit - mv - logf(ex);
}

template <int Fin, int O>
static void run_stage(hipStream_t stream, const uint32_t* mask, const unsigned short* xin,
                      const unsigned short* WT, const float* avec,
                      unsigned short* WhT, float* f1, float* f2,
                      float* pacc, float* lpart) {
    constexpr int CG = (NHEADS * O) / 64;
    k_whgemm<Fin, O><<<256 * CG, 256, 0, stream>>>(xin, WT, avec, WhT, f1, f2);
    k_pv<O><<<NHEADS * 64 * NJS, 256, 0, stream>>>(mask, f1, f2, WhT, pacc, lpart);
}

extern "C" void kernel_launch(void* const* d_in, const int* in_sizes, int n_in,
                              void* d_out, int out_size, void* d_ws, size_t ws_size,
                              hipStream_t stream) {
    const float* x    = (const float*)d_in[0];
    const int*   adj  = (const int*)d_in[1];
    const float* W1   = (const float*)d_in[2];
    const float* a1   = (const float*)d_in[3];
    const float* W2   = (const float*)d_in[4];
    const float* a2   = (const float*)d_in[5];
    const float* W3   = (const float*)d_in[6];
    const float* a3   = (const float*)d_in[7];
    const float* Wlin = (const float*)d_in[8];
    const float* blin = (const float*)d_in[9];
    float* out = (float*)d_out;

    char* ws = (char*)d_ws;
    uint32_t*       mask = (uint32_t*)ws;                                     // 2 MB
    unsigned short* xbf  = (unsigned short*)(ws + (2u << 20));                // 4 MB
    unsigned short* WhT  = (unsigned short*)(ws + (6u << 20));                // 2 MB
    unsigned short* WT1  = (unsigned short*)(ws + (8u << 20));                // 256 KB
    unsigned short* WT2  = (unsigned short*)(ws + (8u << 20) + (256u << 10)); // 64 KB
    unsigned short* WT3  = (unsigned short*)(ws + (8u << 20) + (320u << 10)); // 16 KB
    float*          f1   = (float*)(ws + (8u << 20) + (384u << 10));          // 64 KB
    float*          f2   = (float*)(ws + (8u << 20) + (448u << 10));          // 64 KB
    float*          lpart= (float*)(ws + (8u << 20) + (512u << 10));          // 256 KB
    float*          pacc = (float*)(ws + (9u << 20));                         // 16 MB

    k_pre<<<4096 + 2720, 256, 0, stream>>>(adj, (unsigned short*)mask, x, xbf,
                                           W1, WT1, W2, WT2, W3, WT3);

    run_stage<512, 64>(stream, mask, xbf, WT1, a1, WhT, f1, f2, pacc, lpart);
    k_fin<64><<<NHEADS * NNODES * 64 / 256, 256, 0, stream>>>(pacc, lpart, xbf);
    run_stage<256, 32>(stream, mask, xbf, WT2, a2, WhT, f1, f2, pacc, lpart);
    k_fin<32><<<NHEADS * NNODES * 32 / 256, 256, 0, stream>>>(pacc, lpart, xbf);
    run_stage<128, 16>(stream, mask, xbf, WT3, a3, WhT, f1, f2, pacc, lpart);
    k_fin3final<<<NNODES / 4, 256, 0, stream>>>(pacc, lpart, Wlin, blin, out);
}

// Round 11
// 137.520 us; speedup vs baseline: 1.0771x; 1.0345x over previous
//
#include <hip/hip_runtime.h>
#include <hip/hip_bf16.h>
#include <stdint.h>

typedef __attribute__((ext_vector_type(8))) short short8;
typedef __attribute__((ext_vector_type(4))) float float4v;

#define NHEADS 4
#define NNODES 4096
#define LOG2E 1.4426950408889634f
#define NJS 4
#define PSTR ((size_t)NHEADS * NNODES * 64)    // partial-accum slice stride (floats)
#define LSTR ((size_t)NHEADS * NNODES)         // partial-l slice stride (floats)

__device__ __forceinline__ unsigned short f2b(float x) {
    union { float f; uint32_t u; } v; v.f = x;
    uint32_t u = v.u;
    uint32_t r = (u + 0x7FFFu + ((u >> 16) & 1u)) >> 16;
    return (unsigned short)r;
}
__device__ __forceinline__ uint32_t cvtpk(float lo, float hi) {
    uint32_t r;
    asm("v_cvt_pk_bf16_f32 %0, %1, %2" : "=v"(r) : "v"(lo), "v"(hi));
    return r;
}

#define AS1 __attribute__((address_space(1)))
#define AS3 __attribute__((address_space(3)))
__device__ __forceinline__ void gl_lds16(const void* g, void* l) {
    __builtin_amdgcn_global_load_lds((const AS1 unsigned int*)g,
                                     (AS3 unsigned int*)l, 16, 0, 0);
}

// ---- fused preprocessing: ballot-free adjacency pack + x cast + W transposes ----
__global__ __launch_bounds__(256) void k_pre(const int* __restrict__ adj,
                                             unsigned short* __restrict__ mask16,
                                             const float* __restrict__ x,
                                             unsigned short* __restrict__ xbf,
                                             const float* __restrict__ W1,
                                             unsigned short* __restrict__ WT1,
                                             const float* __restrict__ W2,
                                             unsigned short* __restrict__ WT2,
                                             const float* __restrict__ W3,
                                             unsigned short* __restrict__ WT3) {
    int b = blockIdx.x;
    if (b < 4096) {                         // pack: 16 consecutive j per thread, no ballot
        const int4* ap = (const int4*)(adj + ((size_t)b << 12)) + threadIdx.x * 4;
        int4 a0 = ap[0], a1 = ap[1], a2 = ap[2], a3 = ap[3];
        int v[16] = {a0.x, a0.y, a0.z, a0.w, a1.x, a1.y, a1.z, a1.w,
                     a2.x, a2.y, a2.z, a2.w, a3.x, a3.y, a3.z, a3.w};
        uint32_t bits = 0;
#pragma unroll
        for (int k = 0; k < 16; ++k) bits |= (uint32_t)(v[k] != 0) << k;
        mask16[(b << 8) + threadIdx.x] = (unsigned short)bits;
        return;
    }
    int i = (b - 4096) * 256 + threadIdx.x;
    if (i < 524288) {                       // x: 4096*512 f32, 4 per thread
        float4v v = ((const float4v*)x)[i];
        uint2 r;
        r.x = cvtpk(v[0], v[1]);
        r.y = cvtpk(v[2], v[3]);
        ((uint2*)xbf)[i] = r;
    } else if (i < 524288 + 131072) {       // W1 [4][512][64] -> WT1 [4][64][512]
        int j = i - 524288;
        int o = j & 63, f = (j >> 6) & 511, h = j >> 15;
        WT1[((size_t)(h * 64 + o)) * 512 + f] = f2b(W1[j]);
    } else if (i < 524288 + 131072 + 32768) { // W2 [4][256][32] -> WT2 [4][32][256]
        int j = i - 655360;
        int o = j & 31, f = (j >> 5) & 255, h = j >> 13;
        WT2[((size_t)(h * 32 + o)) * 256 + f] = f2b(W2[j]);
    } else if (i < 524288 + 131072 + 32768 + 8192) { // W3 [4][128][16] -> WT3 [4][16][128]
        int j = i - 688128;
        int o = j & 15, f = (j >> 4) & 127, h = j >> 11;
        WT3[((size_t)(h * 16 + o)) * 128 + f] = f2b(W3[j]);
    }
}

// ---- Wh = x @ W (4-wave K-split) + fused f1/f2 epilogue; writes WhT bf16 only.
//      PO > 0: A-tile is finalized in-prologue from prev stage's partials (fin fusion).
template <int Fin, int O, int PO>
__global__ __launch_bounds__(256) void k_whgemm(const unsigned short* __restrict__ A,
                                                const unsigned short* __restrict__ WT,
                                                const float* __restrict__ avec,
                                                unsigned short* __restrict__ WhT,
                                                float* __restrict__ f1,
                                                float* __restrict__ f2,
                                                const float* __restrict__ pacc,
                                                const float* __restrict__ lpart) {
    __shared__ float scc[4][16][64];
    __shared__ unsigned short sa[(PO > 0) ? 16 * Fin : 1];
    __shared__ float sl[(PO > 0) ? 64 : 1];
    constexpr int HPB = 64 / O;           // complete heads per col-group
    const int rt = blockIdx.x & 255, cg = blockIdx.x >> 8;
    const int wv = threadIdx.x >> 6, lane = threadIdx.x & 63;
    const int il = lane & 15, g = lane >> 4;
    constexpr int kpw = Fin >> 2;
    const int k0 = wv * kpw;

    if constexpr (PO > 0) {
        // phase 0: per (row,h) l-sums
        int t = threadIdx.x;
        if (t < 64) {
            int r = t >> 2, hh = t & 3;
            int n = rt * 16 + r;
            float l = 0.f;
#pragma unroll
            for (int k = 0; k < NJS; ++k) l += lpart[k * LSTR + hh * NNODES + n];
            sl[r * 4 + hh] = l;
        }
        __syncthreads();
        // phase 1: finalize A-tile (divide, elu) -> swizzled bf16 LDS
        constexpr int EPT = 16 * Fin / 256;
#pragma unroll
        for (int q = 0; q < EPT; ++q) {
            int e = q * 256 + t;
            int r = e / Fin, f = e % Fin;
            int hh = f / PO, o = f % PO;
            int n = rt * 16 + r;
            size_t idx = ((size_t)hh * NNODES + n) * PO + o;
            float s = 0.f;
#pragma unroll
            for (int k = 0; k < NJS; ++k) s += pacc[k * PSTR + idx];
            float v = s / sl[r * 4 + hh];
            v = (v > 0.f) ? v : (__expf(v) - 1.f);
            int c = f >> 3, pos = f & 7;
            sa[r * Fin + ((c ^ (r & 7)) << 3) + pos] = f2b(v);
        }
        __syncthreads();
    }

    float4v acc[4];
#pragma unroll
    for (int ot = 0; ot < 4; ++ot) acc[ot] = (float4v){0.f, 0.f, 0.f, 0.f};
    const unsigned short* Arow = A + (size_t)(rt * 16 + il) * Fin + k0 + 8 * g;
    const unsigned short* Bcol = WT + (size_t)(cg * 64 + il) * Fin + k0 + 8 * g;
#pragma unroll
    for (int k = 0; k < kpw; k += 32) {
        short8 af;
        if constexpr (PO > 0) {
            int ch = ((k0 + k) >> 3) + g;
            af = *(const short8*)(sa + il * Fin + ((ch ^ (il & 7)) << 3));
        } else {
            af = *(const short8*)(Arow + k);
        }
#pragma unroll
        for (int ot = 0; ot < 4; ++ot) {
            short8 bf = *(const short8*)(Bcol + (size_t)ot * 16 * Fin + k);
            acc[ot] = __builtin_amdgcn_mfma_f32_16x16x32_bf16(af, bf, acc[ot], 0, 0, 0);
        }
    }
#pragma unroll
    for (int ot = 0; ot < 4; ++ot)
#pragma unroll
        for (int r = 0; r < 4; ++r) scc[wv][g * 4 + r][ot * 16 + il] = acc[ot][r];
    __syncthreads();
    // epilogue 1: WhT bf16 [H][O][N]
    for (int e = threadIdx.x; e < 1024; e += 256) {
        int row = e >> 6, col = e & 63;
        float v = scc[0][row][col] + scc[1][row][col] + scc[2][row][col] + scc[3][row][col];
        int gc = cg * 64 + col;
        int hh = gc / O, o = gc % O;
        WhT[((size_t)(hh * O + o)) * NNODES + rt * 16 + row] = f2b(v);
    }
    // epilogue 2: f1/f2 (each block covers complete heads -> no atomics)
    {
        int hl = lane / O, o = lane % O;
        int h = cg * HPB + hl;
        float av1 = avec[h * 2 * O + o];
        float av2 = avec[h * 2 * O + O + o];
#pragma unroll
        for (int r = 0; r < 4; ++r) {
            int row = wv * 4 + r;
            float v = scc[0][row][lane] + scc[1][row][lane] + scc[2][row][lane] + scc[3][row][lane];
            float s1 = v * av1, s2 = v * av2;
#pragma unroll
            for (int d = O / 2; d > 0; d >>= 1) {
                s1 += __shfl_xor(s1, d);
                s2 += __shfl_xor(s2, d);
            }
            if (o == 0) {
                int n = rt * 16 + row;
                f1[h * NNODES + n] = s1 * LOG2E;
                f2[h * NNODES + n] = s2 * LOG2E;
            }
        }
    }
}

// ---- stage one 64-j B tile ([O rows][64 j] bf16) into LDS, source-swizzled.
//      CH<256: duplicate-stage so all threads issue identical DMA counts. ----
template <int O>
__device__ __forceinline__ void stage_tile(const unsigned short* WB0, int j0,
                                           char* dst, int tid) {
    constexpr int CH = O * 8;   // 16B chunks
#pragma unroll
    for (int q = 0; q < CH; q += 256) {
        int s = (CH >= 256) ? (q + tid) : (tid & (CH - 1));
        int o = s >> 3, c = s & 7;
        int cg = c ^ (o & 7);
        gl_lds16(WB0 + (size_t)o * NNODES + j0 + 8 * cg, dst + s * 16);
    }
}

// ---- fused attention PV: 3-buffer counted-vmcnt pipeline (round-6 verified) ----
template <int O>
__global__ __launch_bounds__(256, 4) void k_pv(const uint32_t* __restrict__ mask,
                                               const float* __restrict__ f1L,
                                               const float* __restrict__ f2L,
                                               const unsigned short* __restrict__ WhT,
                                               float* __restrict__ pacc,
                                               float* __restrict__ lpart) {
    constexpr int NT = O / 16;
    constexpr int CH = O * 8;
    constexpr int LPT = (O == 64) ? 2 : 1;   // uniform DMA ops per thread per tile
    __shared__ unsigned short bt[3][CH * 8];
    __shared__ float sf2[1024];
    __shared__ uint32_t smask[64][34];       // pad 34 -> conflict-free b64 reads
    const int b = blockIdx.x;
    const int js = b & 3, rt = (b >> 2) & 63, h = b >> 8;
    const int tid = threadIdx.x, wv = tid >> 6, lane = tid & 63;
    const int il = lane & 15, g = lane >> 4;
    const int j0b = js * 1024;
    const float* f2h = f2L + h * NNODES;
    const unsigned short* WB0 = WhT + (size_t)h * O * NNODES;
    const int nrow = wv * 16 + il;
    const float f1i = f1L[h * NNODES + rt * 64 + nrow];

    // ---- prologue A: masks -> regs, drain, masks -> LDS
    {
        int r = tid >> 2, c = (tid & 3) * 8;
        const uint32_t* mg = mask + (size_t)(rt * 64 + r) * 128 + js * 32 + c;
        uint4 m0 = *(const uint4*)mg;
        uint4 m1 = *(const uint4*)(mg + 4);
        asm volatile("s_waitcnt vmcnt(0)" ::: "memory");
        uint32_t* dstm = &smask[r][c];
        *(uint2*)(dstm + 0) = make_uint2(m0.x, m0.y);
        *(uint2*)(dstm + 2) = make_uint2(m0.z, m0.w);
        *(uint2*)(dstm + 4) = make_uint2(m1.x, m1.y);
        *(uint2*)(dstm + 6) = make_uint2(m1.z, m1.w);
    }
    gl_lds16(f2h + j0b + tid * 4, (char*)sf2 + tid * 16);
    stage_tile<O>(WB0, j0b, (char*)&bt[0][0], tid);
    stage_tile<O>(WB0, j0b + 64, (char*)&bt[1][0], tid);
    asm volatile("s_waitcnt vmcnt(%0) lgkmcnt(0)" :: "i"(LPT) : "memory");
    __builtin_amdgcn_sched_barrier(0);
    __builtin_amdgcn_s_barrier();

    float4v acc[NT];
#pragma unroll
    for (int ot = 0; ot < NT; ++ot) acc[ot] = (float4v){0.f, 0.f, 0.f, 0.f};
    float4v accl = (float4v){0.f, 0.f, 0.f, 0.f};
    short8 bones;
#pragma unroll
    for (int q = 0; q < 8; ++q) bones[q] = (il == 0) ? (short)0x3F80 : (short)0;

    auto compute = [&](int t) {
        const char* btc = (const char*)&bt[t % 3][0];
        uint2 mw = *(const uint2*)&smask[nrow][2 * t];
        const float* fp0 = sf2 + t * 64 + 8 * g;
#pragma unroll
        for (int s = 0; s < 2; ++s) {
            short8 B[NT];
#pragma unroll
            for (int ot = 0; ot < NT; ++ot) {
                int o = ot * 16 + il;
                B[ot] = *(const short8*)(btc + o * 128 + 16 * (((s << 2) + g) ^ (o & 7)));
            }
            const float* fp = fp0 + s * 32;
            float4v fa = *(const float4v*)fp;
            float4v fb = *(const float4v*)(fp + 4);
            uint32_t word = s ? mw.y : mw.x;
            uint32_t bits = (word >> (8 * g)) & 0xFFu;
            float p[8];
#pragma unroll
            for (int bb = 0; bb < 8; ++bb) {
                float sv = f1i + ((bb < 4) ? fa[bb] : fb[bb - 4]);
                sv = fmaxf(sv, 0.2f * sv);
                float pv = __builtin_amdgcn_exp2f(sv);
                p[bb] = ((bits >> bb) & 1u) ? pv : 0.f;
            }
            union { short8 s8; uint32_t u[4]; } pu;
            pu.u[0] = cvtpk(p[0], p[1]);
            pu.u[1] = cvtpk(p[2], p[3]);
            pu.u[2] = cvtpk(p[4], p[5]);
            pu.u[3] = cvtpk(p[6], p[7]);
#pragma unroll
            for (int ot = 0; ot < NT; ++ot)
                acc[ot] = __builtin_amdgcn_mfma_f32_16x16x32_bf16(pu.s8, B[ot], acc[ot], 0, 0, 0);
            accl = __builtin_amdgcn_mfma_f32_16x16x32_bf16(pu.s8, bones, accl, 0, 0, 0);
        }
    };

#pragma unroll
    for (int t = 0; t < 14; ++t) {
        stage_tile<O>(WB0, j0b + (t + 2) * 64, (char*)&bt[(t + 2) % 3][0], tid);
        compute(t);
        asm volatile("s_waitcnt vmcnt(%0)" :: "i"(LPT) : "memory");
        __builtin_amdgcn_sched_barrier(0);
        __builtin_amdgcn_s_barrier();
    }
    compute(14);
    asm volatile("s_waitcnt vmcnt(0)" ::: "memory");
    __builtin_amdgcn_sched_barrier(0);
    __builtin_amdgcn_s_barrier();
    compute(15);

    // non-atomic disjoint partial stores (slice js owns its buffer)
    float* pj = pacc + js * PSTR + (size_t)h * NNODES * O;
#pragma unroll
    for (int ot = 0; ot < NT; ++ot)
#pragma unroll
        for (int r = 0; r < 4; ++r)
            pj[(size_t)(rt * 64 + wv * 16 + g * 4 + r) * O + ot * 16 + il] = acc[ot][r];
    if (il == 0) {
        float* lj = lpart + js * LSTR + h * NNODES;
#pragma unroll
        for (int r = 0; r < 4; ++r)
            lj[rt * 64 + wv * 16 + g * 4 + r] = accl[r];
    }
}

// ---- stage-3 finalize fused with final linear + log_softmax (LDS handoff) ----
__global__ __launch_bounds__(256) void k_fin3final(const float* __restrict__ pacc,
                                                   const float* __restrict__ lpart,
                                                   const float* __restrict__ Wlin,
                                                   const float* __restrict__ blin,
                                                   float* __restrict__ out) {
    __shared__ float sh3[4][64];
    const int tid = threadIdx.x;
    const int n0 = blockIdx.x * 4;
    {   // finalize 4 rows x 64 features (h*16+o), one element per thread
        int r = tid >> 6, hh = (tid >> 4) & 3, o = tid & 15;
        int n = n0 + r;
        size_t idx = ((size_t)hh * NNODES + n) * 16 + o;
        int li = hh * NNODES + n;
        float s = 0.f, l = 0.f;
#pragma unroll
        for (int k = 0; k < NJS; ++k) {
            s += pacc[k * PSTR + idx];
            l += lpart[k * LSTR + li];
        }
        float v = s / l;
        v = (v > 0.f) ? v : (__expf(v) - 1.f);
        sh3[r][hh * 16 + o] = v;
    }
    __syncthreads();
    int rr = tid >> 6, lane = tid & 63;
    int n = n0 + rr;
    float logit = 0.f;
    if (lane < 40) {
        logit = blin[lane];
#pragma unroll
        for (int k = 0; k < 64; ++k) logit += sh3[rr][k] * Wlin[k * 40 + lane];
    }
    float mv = (lane < 40) ? logit : -3.0e38f;
    for (int d = 32; d > 0; d >>= 1) mv = fmaxf(mv, __shfl_xor(mv, d));
    float ex = (lane < 40) ? __expf(logit - mv) : 0.f;
    for (int d = 32; d > 0; d >>= 1) ex += __shfl_xor(ex, d);
    if (lane < 40) out[n * 40 + lane] = logit - mv - logf(ex);
}

extern "C" void kernel_launch(void* const* d_in, const int* in_sizes, int n_in,
                              void* d_out, int out_size, void* d_ws, size_t ws_size,
                              hipStream_t stream) {
    const float* x    = (const float*)d_in[0];
    const int*   adj  = (const int*)d_in[1];
    const float* W1   = (const float*)d_in[2];
    const float* a1   = (const float*)d_in[3];
    const float* W2   = (const float*)d_in[4];
    const float* a2   = (const float*)d_in[5];
    const float* W3   = (const float*)d_in[6];
    const float* a3   = (const float*)d_in[7];
    const float* Wlin = (const float*)d_in[8];
    const float* blin = (const float*)d_in[9];
    float* out = (float*)d_out;

    char* ws = (char*)d_ws;
    uint32_t*       mask = (uint32_t*)ws;                                     // 2 MB
    unsigned short* xbf  = (unsigned short*)(ws + (2u << 20));                // 4 MB
    unsigned short* WhT  = (unsigned short*)(ws + (6u << 20));                // 2 MB
    unsigned short* WT1  = (unsigned short*)(ws + (8u << 20));                // 256 KB
    unsigned short* WT2  = (unsigned short*)(ws + (8u << 20) + (256u << 10)); // 64 KB
    unsigned short* WT3  = (unsigned short*)(ws + (8u << 20) + (320u << 10)); // 16 KB
    float*          f1   = (float*)(ws + (8u << 20) + (384u << 10));          // 64 KB
    float*          f2   = (float*)(ws + (8u << 20) + (448u << 10));          // 64 KB
    float*          lpart= (float*)(ws + (8u << 20) + (512u << 10));          // 256 KB
    float*          pacc = (float*)(ws + (9u << 20));                         // 16 MB

    k_pre<<<4096 + 2720, 256, 0, stream>>>(adj, (unsigned short*)mask, x, xbf,
                                           W1, WT1, W2, WT2, W3, WT3);

    // stage 1
    k_whgemm<512, 64, 0><<<1024, 256, 0, stream>>>(xbf, WT1, a1, WhT, f1, f2,
                                                   nullptr, nullptr);
    k_pv<64><<<1024, 256, 0, stream>>>(mask, f1, f2, WhT, pacc, lpart);
    // stage 2 (fin of stage 1 fused into A-tile prologue)
    k_whgemm<256, 32, 64><<<512, 256, 0, stream>>>(nullptr, WT2, a2, WhT, f1, f2,
                                                   pacc, lpart);
    k_pv<32><<<1024, 256, 0, stream>>>(mask, f1, f2, WhT, pacc, lpart);
    // stage 3 (fin of stage 2 fused)
    k_whgemm<128, 16, 32><<<256, 256, 0, stream>>>(nullptr, WT3, a3, WhT, f1, f2,
                                                   pacc, lpart);
    k_pv<16><<<1024, 256, 0, stream>>>(mask, f1, f2, WhT, pacc, lpart);
    // stage-3 finalize + final linear + log_softmax
    k_fin3final<<<NNODES / 4, 256, 0, stream>>>(pacc, lpart, Wlin, blin, out);
}